// Round 1
// baseline (1014.054 us; speedup 1.0000x reference)
//
#include <hip/hip_runtime.h>
#include <cmath>

// Problem dims (from setup_inputs): B=4, C=64, H=W=256, k=3
namespace {
constexpr int Bn = 4, Cn = 64, Hn = 256, Wn = 256;
constexpr int HWn = Hn * Wn;              // 65536
// ws layout in floats:
constexpr long PRE_LOW  = 0;              // a_low  preprocessed, NHWC, 16777216
constexpr long PRE_HIGH = 16777216;       // a_high preprocessed, NHWC, 16777216
constexpr long OM_COL   = 33554432;       // om col (B,9,H,W) 2359296
constexpr long OM_ROW   = 35913728;       // om row            2359296
constexpr long W1P      = 38273024;       // [c][j]   64*32
constexpr long W2P      = 38275072;       // [j][o]   32*64
constexpr long WOFF     = 38277120;       // [(c*3+k)][18]  192*18
constexpr long WDC      = 38280576;       // [(c*3+k)][o]   192*64
constexpr long WDR      = 38292864;       // 192*64
// total = 38305152 floats = 153.2 MB
}

__device__ __forceinline__ float4 ld4(const float* p) {
    return *reinterpret_cast<const float4*>(p);
}
__device__ __forceinline__ float comp(const float4& v, int e) {
    return e == 0 ? v.x : e == 1 ? v.y : e == 2 ? v.z : v.w;
}
__device__ __forceinline__ float4 fma4(float w, const float4& g, const float4& s) {
    return make_float4(fmaf(w, g.x, s.x), fmaf(w, g.y, s.y),
                       fmaf(w, g.z, s.z), fmaf(w, g.w, s.w));
}
__device__ __forceinline__ float sigm(float x) { return 1.f / (1.f + __expf(-x)); }

// ---------------- weight repack (tiny) ----------------
__global__ void k_repack(const float* __restrict__ pw1, const float* __restrict__ pw2,
                         const float* __restrict__ owc, const float* __restrict__ owr,
                         const float* __restrict__ wc,  const float* __restrict__ wr,
                         float* __restrict__ ws)
{
    int t = blockIdx.x * blockDim.x + threadIdx.x;
    int stride = gridDim.x * blockDim.x;
    for (int i = t; i < 2048; i += stride) { int c = i >> 5, j = i & 31; ws[W1P + i] = pw1[j * 64 + c]; }
    for (int i = t; i < 2048; i += stride) { int j = i >> 6, o = i & 63; ws[W2P + i] = pw2[o * 32 + j]; }
    for (int i = t; i < 3456; i += stride) {
        int ck = i / 18, d = i - ck * 18;
        ws[WOFF + i] = (d < 9) ? owc[d * 192 + ck] : owr[(d - 9) * 192 + ck];
    }
    for (int i = t; i < 12288; i += stride) {
        int ck = i >> 6, o = i & 63;
        ws[WDC + i] = wc[o * 192 + ck];
        ws[WDR + i] = wr[o * 192 + ck];
    }
}

// ---------------- preprocess: 1x1 conv 64->32->64, NCHW in -> NHWC out ----------------
__global__ __launch_bounds__(256) void k_pre(const float* __restrict__ alow,
                                             const float* __restrict__ ahigh,
                                             const float* __restrict__ b1,
                                             const float* __restrict__ b2,
                                             float* __restrict__ ws)
{
    const float* __restrict__ W1 = ws + W1P;
    const float* __restrict__ W2 = ws + W2P;
    int t = blockIdx.x * 256 + threadIdx.x;      // [0, 2*B*H*W)
    int tensor = t >> 18;
    int pix = t & 262143;
    int b = pix >> 16;
    int hw = pix & 65535;
    const float* __restrict__ x = (tensor ? ahigh : alow) + (long)b * Cn * HWn + hw;
    float* __restrict__ outp = ws + (tensor ? PRE_HIGH : PRE_LOW) + (long)pix * 64;

    float hreg[32];
#pragma unroll
    for (int j = 0; j < 32; j++) hreg[j] = b1[j];
#pragma unroll 4
    for (int c = 0; c < 64; c++) {
        float xv = x[c * HWn];
        const float* wrow = W1 + c * 32;
#pragma unroll
        for (int j = 0; j < 32; j++) hreg[j] = fmaf(wrow[j], xv, hreg[j]);
    }
    float acc[64];
#pragma unroll
    for (int o = 0; o < 64; o++) acc[o] = b2[o];
#pragma unroll
    for (int j = 0; j < 32; j++) {
        float hv = hreg[j];
        const float* wrow = W2 + j * 64;
#pragma unroll
        for (int o = 0; o < 64; o++) acc[o] = fmaf(wrow[o], hv, acc[o]);
    }
#pragma unroll
    for (int o = 0; o < 64; o += 4) {
        *reinterpret_cast<float4*>(outp + o) = make_float4(acc[o], acc[o + 1], acc[o + 2], acc[o + 3]);
    }
}

// ---------------- offset convs (both dirs fused): 9ch 3x1 and 9ch 1x3, zero-pad ----------------
__global__ __launch_bounds__(256) void k_om(const float* __restrict__ ocb,
                                            const float* __restrict__ orb,
                                            float* __restrict__ ws)
{
    const float* __restrict__ A  = ws;          // a_low pre, NHWC
    const float* __restrict__ Wo = ws + WOFF;
    float* __restrict__ omc = ws + OM_COL;
    float* __restrict__ omr = ws + OM_ROW;
    int t = blockIdx.x * 256 + threadIdx.x;     // [0, B*H*W)
    int b = t >> 16, hw = t & 65535, h = hw >> 8, w = hw & 255;
    long rowbase = ((long)b * Hn + h) * Wn;

    float acc[18];
#pragma unroll
    for (int d = 0; d < 18; d++) acc[d] = 0.f;

    for (int c4 = 0; c4 < 16; c4++) {
#pragma unroll
        for (int k = 0; k < 3; k++) {
            int yy = h + k - 1;
            int xx = w + k - 1;
            float4 xc = make_float4(0.f, 0.f, 0.f, 0.f), xr = xc;
            if ((unsigned)yy < (unsigned)Hn)
                xc = ld4(A + (((long)b * Hn + yy) * Wn + w) * 64 + c4 * 4);
            if ((unsigned)xx < (unsigned)Wn)
                xr = ld4(A + (rowbase + xx) * 64 + c4 * 4);
#pragma unroll
            for (int e = 0; e < 4; e++) {
                const float* wrow = Wo + (c4 * 12 + e * 3 + k) * 18;
                float xcv = comp(xc, e);
                float xrv = comp(xr, e);
#pragma unroll
                for (int d = 0; d < 9; d++) acc[d]     = fmaf(wrow[d],     xcv, acc[d]);
#pragma unroll
                for (int d = 0; d < 9; d++) acc[9 + d] = fmaf(wrow[9 + d], xrv, acc[9 + d]);
            }
        }
    }
#pragma unroll
    for (int d = 0; d < 9; d++) omc[((long)b * 9 + d) * HWn + hw] = acc[d] + ocb[d];
#pragma unroll
    for (int d = 0; d < 9; d++) omr[((long)b * 9 + d) * HWn + hw] = acc[9 + d] + orb[d];
}

// ---------------- deformable conv + fused sigmoid-combine ----------------
// MODE 0: column (3x1, ky=k-1), writes out = a_low + sig*a_high
// MODE 1: row (1x3, kx=k-1),    adds   out += a_low + sig*a_high
template <int MODE>
__global__ __launch_bounds__(256) void k_deform(const float* __restrict__ bias,
                                                float* __restrict__ out,
                                                float* __restrict__ ws)
{
    __shared__ float Vt[12288];          // V[(c*3+k)][p], 192 x 64
    __shared__ float posw[4][192];
    __shared__ int   poso[4][192];

    const float* __restrict__ A  = ws;               // a_low pre NHWC
    const float* __restrict__ Ah = ws + PRE_HIGH;    // a_high pre NHWC
    const float* __restrict__ om = ws + (MODE ? OM_ROW : OM_COL);
    const float* __restrict__ Wd = ws + (MODE ? WDR : WDC);

    int blk = blockIdx.x;                 // ((b*H + h)*4 + wt)
    int wt = blk & 3, bh = blk >> 2, h = bh & 255, b = bh >> 8;
    int w0 = wt * 64;
    int tid = threadIdx.x;

    // ---- phase 1: offsets -> corner addrs + folded bilinear weights ----
    if (tid < 192) {
        int p = tid & 63, k = tid >> 6;
        int w = w0 + p;
        long ob = ((long)b * 9 * Hn + h) * Wn + w;
        float dy = om[ob + (long)k * HWn];
        float dx = om[ob + (long)(3 + k) * HWn];
        float mm = om[ob + (long)(6 + k) * HWn];
        float mask = sigm(mm);
        float py = dy + (float)h + (MODE ? 0.f : (float)(k - 1));
        float px = dx + (float)w + (MODE ? (float)(k - 1) : 0.f);
        float fy = floorf(py), fx = floorf(px);
        float ty = py - fy, tx = px - fx;
        int y0 = (int)fy, x0 = (int)fx;
        int y1 = y0 + 1, x1 = x0 + 1;
        float vy0 = ((unsigned)y0 < (unsigned)Hn) ? 1.f : 0.f;
        float vy1 = ((unsigned)y1 < (unsigned)Hn) ? 1.f : 0.f;
        float vx0 = ((unsigned)x0 < (unsigned)Wn) ? 1.f : 0.f;
        float vx1 = ((unsigned)x1 < (unsigned)Wn) ? 1.f : 0.f;
        int y0c = min(max(y0, 0), Hn - 1), y1c = min(max(y1, 0), Hn - 1);
        int x0c = min(max(x0, 0), Wn - 1), x1c = min(max(x1, 0), Wn - 1);
        float ry = 1.f - ty, rx = 1.f - tx;
        posw[0][tid] = ry * rx * mask * vy0 * vx0;
        posw[1][tid] = ry * tx * mask * vy0 * vx1;
        posw[2][tid] = ty * rx * mask * vy1 * vx0;
        posw[3][tid] = ty * tx * mask * vy1 * vx1;
        int pbase = b * HWn;
        poso[0][tid] = (pbase + y0c * Wn + x0c) * 64;
        poso[1][tid] = (pbase + y0c * Wn + x1c) * 64;
        poso[2][tid] = (pbase + y1c * Wn + x0c) * 64;
        poso[3][tid] = (pbase + y1c * Wn + x1c) * 64;
    }
    __syncthreads();

    // ---- phase 2: im2col into LDS. jobs = (c-quarter, k, p) = 768, 3 rounds ----
#pragma unroll
    for (int r = 0; r < 3; r++) {
        int jid = tid + r * 256;
        int c4 = jid / 192;            // 0..3 (never straddles a wave)
        int kp = jid - c4 * 192;       // k*64 + p
        int c0 = c4 * 16;
        float4 s0 = make_float4(0.f, 0.f, 0.f, 0.f), s1 = s0, s2 = s0, s3 = s0;
#pragma unroll
        for (int i = 0; i < 4; i++) {
            const float* g = A + poso[i][kp] + c0;
            float wgt = posw[i][kp];
            s0 = fma4(wgt, ld4(g + 0),  s0);
            s1 = fma4(wgt, ld4(g + 4),  s1);
            s2 = fma4(wgt, ld4(g + 8),  s2);
            s3 = fma4(wgt, ld4(g + 12), s3);
        }
        int k = kp >> 6, p = kp & 63;
#pragma unroll
        for (int e = 0; e < 4; e++) {
            Vt[((c0 + e) * 3 + k) * 64 + p]      = comp(s0, e);
            Vt[((c0 + 4 + e) * 3 + k) * 64 + p]  = comp(s1, e);
            Vt[((c0 + 8 + e) * 3 + k) * 64 + p]  = comp(s2, e);
            Vt[((c0 + 12 + e) * 3 + k) * 64 + p] = comp(s3, e);
        }
    }
    __syncthreads();

    // ---- phase 3: GEMM 64o x 192k x 64p; wave owns 16 o's (scalar weights) ----
    int wv = __builtin_amdgcn_readfirstlane(tid >> 6);
    int lane = tid & 63;
    int obase = wv * 16;
    float acc[16];
#pragma unroll
    for (int i = 0; i < 16; i++) acc[i] = 0.f;
#pragma unroll 2
    for (int kk = 0; kk < 192; kk++) {
        float v = Vt[kk * 64 + lane];
        const float* wrow = Wd + kk * 64 + obase;   // wave-uniform -> s_load
#pragma unroll
        for (int i = 0; i < 16; i++) acc[i] = fmaf(wrow[i], v, acc[i]);
    }

    // ---- epilogue: sigmoid + combine ----
    int w = w0 + lane;
    long pix64 = (((long)b * Hn + h) * Wn + w) * 64;
    long outb = (((long)(b * 64 + obase)) * Hn + h) * Wn + w;
#pragma unroll
    for (int i = 0; i < 16; i++) {
        int o = obase + i;
        float s = sigm(acc[i] + bias[o]);
        float val = A[pix64 + o] + s * Ah[pix64 + o];
        if (MODE) out[outb + (long)i * HWn] += val;
        else      out[outb + (long)i * HWn] = val;
    }
}

extern "C" void kernel_launch(void* const* d_in, const int* in_sizes, int n_in,
                              void* d_out, int out_size, void* d_ws, size_t ws_size,
                              hipStream_t stream)
{
    const float* a_low  = (const float*)d_in[0];
    const float* a_high = (const float*)d_in[1];
    const float* pre_w1 = (const float*)d_in[2];
    const float* pre_b1 = (const float*)d_in[3];
    const float* pre_w2 = (const float*)d_in[4];
    const float* pre_b2 = (const float*)d_in[5];
    const float* offc_w = (const float*)d_in[6];
    const float* offc_b = (const float*)d_in[7];
    const float* wc     = (const float*)d_in[8];
    const float* bc     = (const float*)d_in[9];
    const float* offr_w = (const float*)d_in[10];
    const float* offr_b = (const float*)d_in[11];
    const float* wr     = (const float*)d_in[12];
    const float* br     = (const float*)d_in[13];
    float* out = (float*)d_out;
    float* ws  = (float*)d_ws;

    hipLaunchKernelGGL(k_repack, dim3(126), dim3(256), 0, stream,
                       pre_w1, pre_w2, offc_w, offr_w, wc, wr, ws);
    hipLaunchKernelGGL(k_pre, dim3(2048), dim3(256), 0, stream,
                       a_low, a_high, pre_b1, pre_b2, ws);
    hipLaunchKernelGGL(k_om, dim3(1024), dim3(256), 0, stream,
                       offc_b, offr_b, ws);
    hipLaunchKernelGGL((k_deform<0>), dim3(4096), dim3(256), 0, stream, bc, out, ws);
    hipLaunchKernelGGL((k_deform<1>), dim3(4096), dim3(256), 0, stream, br, out, ws);
}

// Round 2
// 760.171 us; speedup vs baseline: 1.3340x; 1.3340x over previous
//
#include <hip/hip_runtime.h>
#include <cmath>

// Problem dims (from setup_inputs): B=4, C=64, H=W=256, k=3
namespace {
constexpr int Bn = 4, Cn = 64, Hn = 256, Wn = 256;
constexpr int HWn = Hn * Wn;              // 65536
// ws layout in floats:
constexpr long PRE_LOW  = 0;              // a_low  preprocessed, NHWC, 16777216
constexpr long PRE_HIGH = 16777216;       // a_high preprocessed, NHWC, 16777216
constexpr long OM_COL   = 33554432;       // om col (B,9,H,W) 2359296
constexpr long OM_ROW   = 35913728;       // om row            2359296
constexpr long W1P      = 38273024;       // [c][j]   64*32
constexpr long W2P      = 38275072;       // [j][o]   32*64
constexpr long WOFF     = 38277120;       // [(c*3+k)][18]  192*18
constexpr long WDC      = 38280576;       // [(c*3+k)][o]   192*64
constexpr long WDR      = 38292864;       // 192*64
// total = 38305152 floats = 153.2 MB
// NCHW copy of preprocessed a_low lives in d_out (overwritten later by k_deform<0>)
}

__device__ __forceinline__ float4 ld4(const float* p) {
    return *reinterpret_cast<const float4*>(p);
}
__device__ __forceinline__ float comp(const float4& v, int e) {
    return e == 0 ? v.x : e == 1 ? v.y : e == 2 ? v.z : v.w;
}
__device__ __forceinline__ float4 fma4(float w, const float4& g, const float4& s) {
    return make_float4(fmaf(w, g.x, s.x), fmaf(w, g.y, s.y),
                       fmaf(w, g.z, s.z), fmaf(w, g.w, s.w));
}
__device__ __forceinline__ float sigm(float x) { return 1.f / (1.f + __expf(-x)); }

// ---------------- weight repack (tiny) ----------------
__global__ void k_repack(const float* __restrict__ pw1, const float* __restrict__ pw2,
                         const float* __restrict__ owc, const float* __restrict__ owr,
                         const float* __restrict__ wc,  const float* __restrict__ wr,
                         float* __restrict__ ws)
{
    int t = blockIdx.x * blockDim.x + threadIdx.x;
    int stride = gridDim.x * blockDim.x;
    for (int i = t; i < 2048; i += stride) { int c = i >> 5, j = i & 31; ws[W1P + i] = pw1[j * 64 + c]; }
    for (int i = t; i < 2048; i += stride) { int j = i >> 6, o = i & 63; ws[W2P + i] = pw2[o * 32 + j]; }
    for (int i = t; i < 3456; i += stride) {
        int ck = i / 18, d = i - ck * 18;
        ws[WOFF + i] = (d < 9) ? owc[d * 192 + ck] : owr[(d - 9) * 192 + ck];
    }
    for (int i = t; i < 12288; i += stride) {
        int ck = i >> 6, o = i & 63;
        ws[WDC + i] = wc[o * 192 + ck];
        ws[WDR + i] = wr[o * 192 + ck];
    }
}

// ---------------- preprocess: 1x1 conv 64->32->64 ----------------
// NCHW in -> NHWC out (both tensors) + NCHW out for a_low (into d_out scratch)
__global__ __launch_bounds__(256) void k_pre(const float* __restrict__ alow,
                                             const float* __restrict__ ahigh,
                                             const float* __restrict__ b1,
                                             const float* __restrict__ b2,
                                             float* __restrict__ ws,
                                             float* __restrict__ anchw)
{
    const float* __restrict__ W1 = ws + W1P;
    const float* __restrict__ W2 = ws + W2P;
    int t = blockIdx.x * 256 + threadIdx.x;      // [0, 2*B*H*W)
    int tensor = t >> 18;
    int pix = t & 262143;
    int b = pix >> 16;
    int hw = pix & 65535;
    const float* __restrict__ x = (tensor ? ahigh : alow) + (long)b * Cn * HWn + hw;
    float* __restrict__ outp = ws + (tensor ? PRE_HIGH : PRE_LOW) + (long)pix * 64;

    float hreg[32];
#pragma unroll
    for (int j = 0; j < 32; j++) hreg[j] = b1[j];
#pragma unroll 4
    for (int c = 0; c < 64; c++) {
        float xv = x[c * HWn];
        const float* wrow = W1 + c * 32;
#pragma unroll
        for (int j = 0; j < 32; j++) hreg[j] = fmaf(wrow[j], xv, hreg[j]);
    }
    float acc[64];
#pragma unroll
    for (int o = 0; o < 64; o++) acc[o] = b2[o];
#pragma unroll
    for (int j = 0; j < 32; j++) {
        float hv = hreg[j];
        const float* wrow = W2 + j * 64;
#pragma unroll
        for (int o = 0; o < 64; o++) acc[o] = fmaf(wrow[o], hv, acc[o]);
    }
#pragma unroll
    for (int o = 0; o < 64; o += 4) {
        *reinterpret_cast<float4*>(outp + o) = make_float4(acc[o], acc[o + 1], acc[o + 2], acc[o + 3]);
    }
    if (tensor == 0) {
        float* __restrict__ np = anchw + (long)b * Cn * HWn + hw;
#pragma unroll
        for (int o = 0; o < 64; o++) np[(long)o * HWn] = acc[o];
    }
}

// ---------------- offset convs from NCHW copy: coalesced, L1-friendly ----------------
// thread = (w, 2-row group). 8 loads : 108 FMA per c. Weights via wave-uniform s_load.
__global__ __launch_bounds__(256) void k_om2(const float* __restrict__ Anc,
                                             const float* __restrict__ ocb,
                                             const float* __restrict__ orb,
                                             float* __restrict__ ws)
{
    const float* __restrict__ Wo = ws + WOFF;
    float* __restrict__ omc = ws + OM_COL;
    float* __restrict__ omr = ws + OM_ROW;
    const int w = threadIdx.x;          // 0..255
    const int g = blockIdx.x & 127;     // 2-row group
    const int b = blockIdx.x >> 7;
    const int h0 = g << 1;
    const float* __restrict__ base = Anc + ((long)b * Cn) * HWn + (long)h0 * Wn + w;

    float accC[2][9], accR[2][9];
#pragma unroll
    for (int r = 0; r < 2; r++)
#pragma unroll
        for (int d = 0; d < 9; d++) { accC[r][d] = 0.f; accR[r][d] = 0.f; }

    const bool topOK = (h0 > 0);
    const bool botOK = (h0 + 2 < Hn);
    const bool wmOK = (w > 0);
    const bool wpOK = (w < Wn - 1);
    const int offT = topOK ? -Wn : 0;
    const int offB = botOK ? 2 * Wn : 0;
    const int offM = wmOK ? -1 : 0;
    const int offP = wpOK ? 1 : 0;

#pragma unroll 2
    for (int c = 0; c < 64; c++) {
        const float* pc = base + (long)c * HWn;
        float vm = pc[offT]; vm = topOK ? vm : 0.f;
        float v0 = pc[0];
        float v1 = pc[Wn];
        float vp = pc[offB]; vp = botOK ? vp : 0.f;
        float h0m = pc[offM];      h0m = wmOK ? h0m : 0.f;
        float h0p = pc[offP];      h0p = wpOK ? h0p : 0.f;
        float h1m = pc[Wn + offM]; h1m = wmOK ? h1m : 0.f;
        float h1p = pc[Wn + offP]; h1p = wpOK ? h1p : 0.f;
        const float* wk0 = Wo + (c * 3) * 18;
        const float* wk1 = wk0 + 18;
        const float* wk2 = wk0 + 36;
#pragma unroll
        for (int d = 0; d < 9; d++) {
            float wc0 = wk0[d], wc1 = wk1[d], wc2 = wk2[d];
            accC[0][d] = fmaf(wc0, vm, fmaf(wc1, v0, fmaf(wc2, v1, accC[0][d])));
            accC[1][d] = fmaf(wc0, v0, fmaf(wc1, v1, fmaf(wc2, vp, accC[1][d])));
            float wr0 = wk0[9 + d], wr1 = wk1[9 + d], wr2 = wk2[9 + d];
            accR[0][d] = fmaf(wr0, h0m, fmaf(wr1, v0, fmaf(wr2, h0p, accR[0][d])));
            accR[1][d] = fmaf(wr0, h1m, fmaf(wr1, v1, fmaf(wr2, h1p, accR[1][d])));
        }
    }

    long ob = ((long)b * 9) * HWn + (long)h0 * Wn + w;
#pragma unroll
    for (int d = 0; d < 9; d++) {
        float bc = ocb[d], br = orb[d];
#pragma unroll
        for (int r = 0; r < 2; r++) {
            omc[ob + (long)d * HWn + r * Wn] = accC[r][d] + bc;
            omr[ob + (long)d * HWn + r * Wn] = accR[r][d] + br;
        }
    }
}

// ---------------- deformable conv + fused sigmoid-combine ----------------
// MODE 0: column (3x1, ky=k-1), writes out = a_low + sig*a_high
// MODE 1: row (1x3, kx=k-1),    adds   out += a_low + sig*a_high
template <int MODE>
__global__ __launch_bounds__(256) void k_deform(const float* __restrict__ bias,
                                                float* __restrict__ out,
                                                float* __restrict__ ws)
{
    __shared__ float Vt[12288];          // V[(c*3+k)][p], 192 x 64
    __shared__ float posw[4][192];
    __shared__ int   poso[4][192];

    const float* __restrict__ A  = ws;               // a_low pre NHWC
    const float* __restrict__ Ah = ws + PRE_HIGH;    // a_high pre NHWC
    const float* __restrict__ om = ws + (MODE ? OM_ROW : OM_COL);
    const float* __restrict__ Wd = ws + (MODE ? WDR : WDC);

    int blk = blockIdx.x;                 // ((b*H + h)*4 + wt)
    int wt = blk & 3, bh = blk >> 2, h = bh & 255, b = bh >> 8;
    int w0 = wt * 64;
    int tid = threadIdx.x;

    // ---- phase 1: offsets -> corner addrs + folded bilinear weights ----
    if (tid < 192) {
        int p = tid & 63, k = tid >> 6;
        int w = w0 + p;
        long ob = ((long)b * 9 * Hn + h) * Wn + w;
        float dy = om[ob + (long)k * HWn];
        float dx = om[ob + (long)(3 + k) * HWn];
        float mm = om[ob + (long)(6 + k) * HWn];
        float mask = sigm(mm);
        float py = dy + (float)h + (MODE ? 0.f : (float)(k - 1));
        float px = dx + (float)w + (MODE ? (float)(k - 1) : 0.f);
        float fy = floorf(py), fx = floorf(px);
        float ty = py - fy, tx = px - fx;
        int y0 = (int)fy, x0 = (int)fx;
        int y1 = y0 + 1, x1 = x0 + 1;
        float vy0 = ((unsigned)y0 < (unsigned)Hn) ? 1.f : 0.f;
        float vy1 = ((unsigned)y1 < (unsigned)Hn) ? 1.f : 0.f;
        float vx0 = ((unsigned)x0 < (unsigned)Wn) ? 1.f : 0.f;
        float vx1 = ((unsigned)x1 < (unsigned)Wn) ? 1.f : 0.f;
        int y0c = min(max(y0, 0), Hn - 1), y1c = min(max(y1, 0), Hn - 1);
        int x0c = min(max(x0, 0), Wn - 1), x1c = min(max(x1, 0), Wn - 1);
        float ry = 1.f - ty, rx = 1.f - tx;
        posw[0][tid] = ry * rx * mask * vy0 * vx0;
        posw[1][tid] = ry * tx * mask * vy0 * vx1;
        posw[2][tid] = ty * rx * mask * vy1 * vx0;
        posw[3][tid] = ty * tx * mask * vy1 * vx1;
        int pbase = b * HWn;
        poso[0][tid] = (pbase + y0c * Wn + x0c) * 64;
        poso[1][tid] = (pbase + y0c * Wn + x1c) * 64;
        poso[2][tid] = (pbase + y1c * Wn + x0c) * 64;
        poso[3][tid] = (pbase + y1c * Wn + x1c) * 64;
    }
    __syncthreads();

    // ---- phase 2: im2col into LDS. jobs = (c-quarter, k, p) = 768, 3 rounds ----
#pragma unroll
    for (int r = 0; r < 3; r++) {
        int jid = tid + r * 256;
        int c4 = jid / 192;            // 0..3 (never straddles a wave)
        int kp = jid - c4 * 192;       // k*64 + p
        int c0 = c4 * 16;
        float4 s0 = make_float4(0.f, 0.f, 0.f, 0.f), s1 = s0, s2 = s0, s3 = s0;
#pragma unroll
        for (int i = 0; i < 4; i++) {
            const float* g = A + poso[i][kp] + c0;
            float wgt = posw[i][kp];
            s0 = fma4(wgt, ld4(g + 0),  s0);
            s1 = fma4(wgt, ld4(g + 4),  s1);
            s2 = fma4(wgt, ld4(g + 8),  s2);
            s3 = fma4(wgt, ld4(g + 12), s3);
        }
        int k = kp >> 6, p = kp & 63;
#pragma unroll
        for (int e = 0; e < 4; e++) {
            Vt[((c0 + e) * 3 + k) * 64 + p]      = comp(s0, e);
            Vt[((c0 + 4 + e) * 3 + k) * 64 + p]  = comp(s1, e);
            Vt[((c0 + 8 + e) * 3 + k) * 64 + p]  = comp(s2, e);
            Vt[((c0 + 12 + e) * 3 + k) * 64 + p] = comp(s3, e);
        }
    }
    __syncthreads();

    // ---- phase 3: GEMM 64o x 192k x 64p; wave owns 16 o's (scalar weights) ----
    int wv = __builtin_amdgcn_readfirstlane(tid >> 6);
    int lane = tid & 63;
    int obase = wv * 16;
    float acc[16];
#pragma unroll
    for (int i = 0; i < 16; i++) acc[i] = 0.f;
#pragma unroll 2
    for (int kk = 0; kk < 192; kk++) {
        float v = Vt[kk * 64 + lane];
        const float* wrow = Wd + kk * 64 + obase;   // wave-uniform -> s_load
#pragma unroll
        for (int i = 0; i < 16; i++) acc[i] = fmaf(wrow[i], v, acc[i]);
    }

    // ---- epilogue: sigmoid + combine ----
    int w = w0 + lane;
    long pix64 = (((long)b * Hn + h) * Wn + w) * 64;
    long outb = (((long)(b * 64 + obase)) * Hn + h) * Wn + w;
#pragma unroll
    for (int i = 0; i < 16; i++) {
        int o = obase + i;
        float s = sigm(acc[i] + bias[o]);
        float val = A[pix64 + o] + s * Ah[pix64 + o];
        if (MODE) out[outb + (long)i * HWn] += val;
        else      out[outb + (long)i * HWn] = val;
    }
}

extern "C" void kernel_launch(void* const* d_in, const int* in_sizes, int n_in,
                              void* d_out, int out_size, void* d_ws, size_t ws_size,
                              hipStream_t stream)
{
    const float* a_low  = (const float*)d_in[0];
    const float* a_high = (const float*)d_in[1];
    const float* pre_w1 = (const float*)d_in[2];
    const float* pre_b1 = (const float*)d_in[3];
    const float* pre_w2 = (const float*)d_in[4];
    const float* pre_b2 = (const float*)d_in[5];
    const float* offc_w = (const float*)d_in[6];
    const float* offc_b = (const float*)d_in[7];
    const float* wc     = (const float*)d_in[8];
    const float* bc     = (const float*)d_in[9];
    const float* offr_w = (const float*)d_in[10];
    const float* offr_b = (const float*)d_in[11];
    const float* wr     = (const float*)d_in[12];
    const float* br     = (const float*)d_in[13];
    float* out = (float*)d_out;
    float* ws  = (float*)d_ws;

    hipLaunchKernelGGL(k_repack, dim3(126), dim3(256), 0, stream,
                       pre_w1, pre_w2, offc_w, offr_w, wc, wr, ws);
    // k_pre also writes NCHW copy of preprocessed a_low into d_out (scratch;
    // fully overwritten later by k_deform<0>)
    hipLaunchKernelGGL(k_pre, dim3(2048), dim3(256), 0, stream,
                       a_low, a_high, pre_b1, pre_b2, ws, out);
    hipLaunchKernelGGL(k_om2, dim3(512), dim3(256), 0, stream,
                       out, offc_b, offr_b, ws);
    hipLaunchKernelGGL((k_deform<0>), dim3(4096), dim3(256), 0, stream, bc, out, ws);
    hipLaunchKernelGGL((k_deform<1>), dim3(4096), dim3(256), 0, stream, br, out, ws);
}

// Round 3
// 277.007 us; speedup vs baseline: 3.6607x; 2.7442x over previous
//
#include <hip/hip_runtime.h>
#include <hip/hip_bf16.h>
#include <cmath>

// Problem dims: B=4, C=64, H=W=256, k=3
namespace {
constexpr int Bn = 4, Cn = 64, Hn = 256, Wn = 256;
constexpr int HWn = Hn * Wn;              // 65536
// ws layout, BYTE offsets:
constexpr size_t OFF_PRE_LOW  = 0;          // a_low pre, NHWC bf16, 33554432 B
constexpr size_t OFF_PRE_HIGH = 33554432;   // a_high pre, NHWC bf16
constexpr size_t OFF_OM_COL   = 67108864;   // om col (B,9,H,W) f32, 9437184 B
constexpr size_t OFF_OM_ROW   = 76546048;   // om row f32
constexpr size_t OFF_W1       = 85983232;   // [c][j] 64*32 f32
constexpr size_t OFF_W2       = 85991424;   // [j][o] 32*64 f32
constexpr size_t OFF_WOFF     = 85999616;   // [(c*3+k)][18] f32
constexpr size_t OFF_WPACK    = 86013440;   // MFMA A-frag packed bf16, 2*12288
// total ~86 MB
}

typedef __attribute__((ext_vector_type(8))) short bf16x8;
typedef __attribute__((ext_vector_type(4))) float f32x4;

__device__ __forceinline__ float sigm(float x) { return 1.f / (1.f + __expf(-x)); }
__device__ __forceinline__ ushort f2bf(float x) {
    __hip_bfloat16 h = __float2bfloat16(x);
    return __builtin_bit_cast(ushort, h);
}
__device__ __forceinline__ float bf2f(ushort u) {
    return __uint_as_float(((unsigned)u) << 16);
}
__device__ __forceinline__ unsigned pk2(float a, float b) {
    return (unsigned)f2bf(a) | ((unsigned)f2bf(b) << 16);
}
__device__ __forceinline__ float bflo(unsigned u) { return __uint_as_float(u << 16); }
__device__ __forceinline__ float bfhi(unsigned u) { return __uint_as_float(u & 0xffff0000u); }

__device__ __forceinline__ void fma8(uint4 u, float wgt, float* s) {
    s[0] = fmaf(wgt, bflo(u.x), s[0]); s[1] = fmaf(wgt, bfhi(u.x), s[1]);
    s[2] = fmaf(wgt, bflo(u.y), s[2]); s[3] = fmaf(wgt, bfhi(u.y), s[3]);
    s[4] = fmaf(wgt, bflo(u.z), s[4]); s[5] = fmaf(wgt, bfhi(u.z), s[5]);
    s[6] = fmaf(wgt, bflo(u.w), s[6]); s[7] = fmaf(wgt, bfhi(u.w), s[7]);
}

// ---------------- weight repack ----------------
__global__ void k_repack(const float* __restrict__ pw1, const float* __restrict__ pw2,
                         const float* __restrict__ owc, const float* __restrict__ owr,
                         const float* __restrict__ wc,  const float* __restrict__ wr,
                         char* __restrict__ ws8)
{
    float*  W1 = (float*)(ws8 + OFF_W1);
    float*  W2 = (float*)(ws8 + OFF_W2);
    float*  Wo = (float*)(ws8 + OFF_WOFF);
    ushort* Wp = (ushort*)(ws8 + OFF_WPACK);
    int t = blockIdx.x * 256 + threadIdx.x;
    int stride = gridDim.x * 256;
    for (int i = t; i < 2048; i += stride) { int c = i >> 5, j = i & 31; W1[i] = pw1[j * 64 + c]; }
    for (int i = t; i < 2048; i += stride) { int j = i >> 6, o = i & 63; W2[i] = pw2[o * 32 + j]; }
    for (int i = t; i < 3456; i += stride) {
        int ck = i / 18, d = i - ck * 18;
        Wo[i] = (d < 9) ? owc[d * 192 + ck] : owr[(d - 9) * 192 + ck];
    }
    // MFMA A-fragment pack: k' = tap*64 + c (permuted K); per mode:
    // Wp[((s*4+wv)*64 + lane)*8 + e] = w[o=wv*16+(lane&15)][k'=32s+(lane>>4)*8+e]
    for (int i = t; i < 24576; i += stride) {
        int m = i >= 12288;
        int rem = i - m * 12288;
        int e = rem & 7, l = (rem >> 3) & 63, wv = (rem >> 9) & 3, s = rem >> 11;
        int kk = 32 * s + (l >> 4) * 8 + e;
        int o = wv * 16 + (l & 15);
        int c = kk & 63, tap = kk >> 6;
        const float* src = m ? wr : wc;
        Wp[i] = f2bf(src[o * 192 + c * 3 + tap]);
    }
}

// ---------------- preprocess: 1x1 conv 64->32->64 ----------------
// NCHW f32 in -> NHWC bf16 (ws) + NCHW bf16 copy of a_low (d_out scratch)
__global__ __launch_bounds__(256) void k_pre(const float* __restrict__ alow,
                                             const float* __restrict__ ahigh,
                                             const float* __restrict__ b1,
                                             const float* __restrict__ b2,
                                             char* __restrict__ ws8,
                                             ushort* __restrict__ anchw)
{
    const float* __restrict__ W1 = (const float*)(ws8 + OFF_W1);
    const float* __restrict__ W2 = (const float*)(ws8 + OFF_W2);
    int t = blockIdx.x * 256 + threadIdx.x;      // [0, 2*B*H*W)
    int tensor = t >> 18;
    int pix = t & 262143;
    int b = pix >> 16;
    int hw = pix & 65535;
    const float* __restrict__ x = (tensor ? ahigh : alow) + (long)b * Cn * HWn + hw;
    ushort* __restrict__ outp = (ushort*)(ws8 + (tensor ? OFF_PRE_HIGH : OFF_PRE_LOW)) + (long)pix * 64;

    float hreg[32];
#pragma unroll
    for (int j = 0; j < 32; j++) hreg[j] = b1[j];
#pragma unroll 4
    for (int c = 0; c < 64; c++) {
        float xv = x[c * HWn];
        const float* wrow = W1 + c * 32;
#pragma unroll
        for (int j = 0; j < 32; j++) hreg[j] = fmaf(wrow[j], xv, hreg[j]);
    }
    float acc[64];
#pragma unroll
    for (int o = 0; o < 64; o++) acc[o] = b2[o];
#pragma unroll
    for (int j = 0; j < 32; j++) {
        float hv = hreg[j];
        const float* wrow = W2 + j * 64;
#pragma unroll
        for (int o = 0; o < 64; o++) acc[o] = fmaf(wrow[o], hv, acc[o]);
    }
#pragma unroll
    for (int o = 0; o < 64; o += 8) {
        uint4 u;
        u.x = pk2(acc[o + 0], acc[o + 1]); u.y = pk2(acc[o + 2], acc[o + 3]);
        u.z = pk2(acc[o + 4], acc[o + 5]); u.w = pk2(acc[o + 6], acc[o + 7]);
        *reinterpret_cast<uint4*>(outp + o) = u;
    }
    if (tensor == 0) {
        ushort* __restrict__ np = anchw + (long)b * Cn * HWn + hw;
#pragma unroll
        for (int o = 0; o < 64; o++) np[(long)o * HWn] = f2bf(acc[o]);
    }
}

// ---------------- offset convs from NCHW bf16 copy ----------------
__global__ __launch_bounds__(256) void k_om2(const ushort* __restrict__ Anc,
                                             const float* __restrict__ ocb,
                                             const float* __restrict__ orb,
                                             char* __restrict__ ws8)
{
    const float* __restrict__ Wo = (const float*)(ws8 + OFF_WOFF);
    float* __restrict__ omc = (float*)(ws8 + OFF_OM_COL);
    float* __restrict__ omr = (float*)(ws8 + OFF_OM_ROW);
    const int w = threadIdx.x;          // 0..255
    const int g = blockIdx.x & 127;     // 2-row group
    const int b = blockIdx.x >> 7;
    const int h0 = g << 1;
    const ushort* __restrict__ base = Anc + ((long)b * Cn) * HWn + (long)h0 * Wn + w;

    float accC[2][9], accR[2][9];
#pragma unroll
    for (int r = 0; r < 2; r++)
#pragma unroll
        for (int d = 0; d < 9; d++) { accC[r][d] = 0.f; accR[r][d] = 0.f; }

    const bool topOK = (h0 > 0);
    const bool botOK = (h0 + 2 < Hn);
    const bool wmOK = (w > 0);
    const bool wpOK = (w < Wn - 1);
    const int offT = topOK ? -Wn : 0;
    const int offB = botOK ? 2 * Wn : 0;
    const int offM = wmOK ? -1 : 0;
    const int offP = wpOK ? 1 : 0;

#pragma unroll 2
    for (int c = 0; c < 64; c++) {
        const ushort* pc = base + (long)c * HWn;
        float vm = bf2f(pc[offT]); vm = topOK ? vm : 0.f;
        float v0 = bf2f(pc[0]);
        float v1 = bf2f(pc[Wn]);
        float vp = bf2f(pc[offB]); vp = botOK ? vp : 0.f;
        float h0m = bf2f(pc[offM]);      h0m = wmOK ? h0m : 0.f;
        float h0p = bf2f(pc[offP]);      h0p = wpOK ? h0p : 0.f;
        float h1m = bf2f(pc[Wn + offM]); h1m = wmOK ? h1m : 0.f;
        float h1p = bf2f(pc[Wn + offP]); h1p = wpOK ? h1p : 0.f;
        const float* wk0 = Wo + (c * 3) * 18;
        const float* wk1 = wk0 + 18;
        const float* wk2 = wk0 + 36;
#pragma unroll
        for (int d = 0; d < 9; d++) {
            float wc0 = wk0[d], wc1 = wk1[d], wc2 = wk2[d];
            accC[0][d] = fmaf(wc0, vm, fmaf(wc1, v0, fmaf(wc2, v1, accC[0][d])));
            accC[1][d] = fmaf(wc0, v0, fmaf(wc1, v1, fmaf(wc2, vp, accC[1][d])));
            float wr0 = wk0[9 + d], wr1 = wk1[9 + d], wr2 = wk2[9 + d];
            accR[0][d] = fmaf(wr0, h0m, fmaf(wr1, v0, fmaf(wr2, h0p, accR[0][d])));
            accR[1][d] = fmaf(wr0, h1m, fmaf(wr1, v1, fmaf(wr2, h1p, accR[1][d])));
        }
    }

    long ob = ((long)b * 9) * HWn + (long)h0 * Wn + w;
#pragma unroll
    for (int d = 0; d < 9; d++) {
        float bc = ocb[d], br = orb[d];
#pragma unroll
        for (int r = 0; r < 2; r++) {
            omc[ob + (long)d * HWn + r * Wn] = accC[r][d] + bc;
            omr[ob + (long)d * HWn + r * Wn] = accR[r][d] + br;
        }
    }
}

// ---------------- fused deformable conv (both dirs) + MFMA + epilogue ----------------
// Per block: 64 pixels (b, h, w0..w0+63). V layout in LDS = MFMA B-frags with
// permuted K: k' = tap*64 + c; VB[g][p][e] (g=k'/8, e=k'%7+1... e=k'&7), 16B rows.
__device__ __forceinline__ void im2col_mode(int m, int tid, const ushort* __restrict__ A16,
                                            ushort* VB,
                                            const float (*posw)[4][192], const int (*poso)[4][192])
{
#pragma unroll
    for (int r = 0; r < 3; r++) {
        int jid = tid + r * 256;
        int c4 = jid / 192;            // wave-uniform (192 | 64-chunks)
        int kp = jid - c4 * 192;
        int tap = kp >> 6, p = kp & 63, c0 = c4 * 16;
        float s[16];
#pragma unroll
        for (int i = 0; i < 16; i++) s[i] = 0.f;
#pragma unroll
        for (int i = 0; i < 4; i++) {
            const ushort* gp = A16 + poso[m][i][kp] + c0;
            float wgt = posw[m][i][kp];
            uint4 ua = *reinterpret_cast<const uint4*>(gp);
            uint4 ub = *reinterpret_cast<const uint4*>(gp + 8);
            fma8(ua, wgt, s);
            fma8(ub, wgt, s + 8);
        }
        int g0 = tap * 8 + c4 * 2;
        uint4 lo, hi;
        lo.x = pk2(s[0], s[1]);  lo.y = pk2(s[2], s[3]);
        lo.z = pk2(s[4], s[5]);  lo.w = pk2(s[6], s[7]);
        hi.x = pk2(s[8], s[9]);  hi.y = pk2(s[10], s[11]);
        hi.z = pk2(s[12], s[13]); hi.w = pk2(s[14], s[15]);
        *reinterpret_cast<uint4*>(&VB[(g0 + 0) * 512 + p * 8]) = lo;
        *reinterpret_cast<uint4*>(&VB[(g0 + 1) * 512 + p * 8]) = hi;
    }
}

__device__ __forceinline__ void gemm_mode(const ushort* VB, const ushort* __restrict__ wpk,
                                          int wvs, int lane, f32x4 acc[4])
{
    int kb = lane >> 4, n = lane & 15;
    const bf16x8* __restrict__ Wp = reinterpret_cast<const bf16x8*>(wpk);
    bf16x8 af[6];
#pragma unroll
    for (int s = 0; s < 6; s++) af[s] = Wp[(s * 4 + wvs) * 64 + lane];
#pragma unroll
    for (int s = 0; s < 6; s++) {
#pragma unroll
        for (int pt = 0; pt < 4; pt++) {
            bf16x8 bf = *reinterpret_cast<const bf16x8*>(VB + (s * 4 + kb) * 512 + (pt * 16 + n) * 8);
            acc[pt] = __builtin_amdgcn_mfma_f32_16x16x32_bf16(af[s], bf, acc[pt], 0, 0, 0);
        }
    }
}

__global__ __launch_bounds__(256, 4) void k_dfuse(const float* __restrict__ bc,
                                                  const float* __restrict__ br,
                                                  float* __restrict__ out,
                                                  char* __restrict__ ws8)
{
    __shared__ __align__(16) ushort VB[12288];    // 24 KB
    __shared__ float posw[2][4][192];             // 6 KB
    __shared__ int   poso[2][4][192];             // 6 KB

    const ushort* __restrict__ A16  = (const ushort*)(ws8 + OFF_PRE_LOW);
    const ushort* __restrict__ Ah16 = (const ushort*)(ws8 + OFF_PRE_HIGH);
    const ushort* __restrict__ wpk  = (const ushort*)(ws8 + OFF_WPACK);

    int blk = blockIdx.x;                 // ((b*H + h)*4 + wt)
    int wt = blk & 3, bh = blk >> 2, h = bh & 255, b = bh >> 8;
    int w0 = wt * 64;
    int tid = threadIdx.x;
    int lane = tid & 63;
    int wvs = __builtin_amdgcn_readfirstlane(tid >> 6);

    // ---- phase 1: decode offsets for BOTH modes ----
#pragma unroll
    for (int r = 0; r < 2; r++) {
        int j = tid + r * 256;
        if (j < 384) {
            int m = j >= 192 ? 1 : 0;
            int jj = j - m * 192;
            int p = jj & 63, k = jj >> 6;
            int w = w0 + p;
            const float* __restrict__ om = (const float*)(ws8 + (m ? OFF_OM_ROW : OFF_OM_COL));
            size_t ob = ((size_t)b * 9 * Hn + h) * Wn + w;
            float dy = om[ob + (size_t)k * HWn];
            float dx = om[ob + (size_t)(3 + k) * HWn];
            float mm = om[ob + (size_t)(6 + k) * HWn];
            float mask = sigm(mm);
            float py = dy + (float)h + (m ? 0.f : (float)(k - 1));
            float px = dx + (float)w + (m ? (float)(k - 1) : 0.f);
            float fy = floorf(py), fx = floorf(px);
            float ty = py - fy, tx = px - fx;
            int y0 = (int)fy, x0 = (int)fx;
            int y1 = y0 + 1, x1 = x0 + 1;
            float vy0 = ((unsigned)y0 < (unsigned)Hn) ? 1.f : 0.f;
            float vy1 = ((unsigned)y1 < (unsigned)Hn) ? 1.f : 0.f;
            float vx0 = ((unsigned)x0 < (unsigned)Wn) ? 1.f : 0.f;
            float vx1 = ((unsigned)x1 < (unsigned)Wn) ? 1.f : 0.f;
            int y0c = min(max(y0, 0), Hn - 1), y1c = min(max(y1, 0), Hn - 1);
            int x0c = min(max(x0, 0), Wn - 1), x1c = min(max(x1, 0), Wn - 1);
            float ry = 1.f - ty, rx = 1.f - tx;
            posw[m][0][jj] = ry * rx * mask * vy0 * vx0;
            posw[m][1][jj] = ry * tx * mask * vy0 * vx1;
            posw[m][2][jj] = ty * rx * mask * vy1 * vx0;
            posw[m][3][jj] = ty * tx * mask * vy1 * vx1;
            int pbase = b * HWn;
            poso[m][0][jj] = (pbase + y0c * Wn + x0c) * 64;
            poso[m][1][jj] = (pbase + y0c * Wn + x1c) * 64;
            poso[m][2][jj] = (pbase + y1c * Wn + x0c) * 64;
            poso[m][3][jj] = (pbase + y1c * Wn + x1c) * 64;
        }
    }
    __syncthreads();

    f32x4 zero = {0.f, 0.f, 0.f, 0.f};
    f32x4 accC[4] = {zero, zero, zero, zero};
    f32x4 accR[4] = {zero, zero, zero, zero};

    im2col_mode(0, tid, A16, VB, posw, poso);
    __syncthreads();
    gemm_mode(VB, wpk, wvs, lane, accC);
    __syncthreads();
    im2col_mode(1, tid, A16, VB, posw, poso);
    __syncthreads();
    gemm_mode(VB, wpk + 12288, wvs, lane, accR);

    // ---- epilogue: out = 2*a_low + (sig_c + sig_r) * a_high ----
    int kb = lane >> 4, n = lane & 15;
    int o0 = wvs * 16 + kb * 4;
    float bcv[4], brv[4];
#pragma unroll
    for (int rg = 0; rg < 4; rg++) { bcv[rg] = bc[o0 + rg]; brv[rg] = br[o0 + rg]; }
#pragma unroll
    for (int pt = 0; pt < 4; pt++) {
        int w = w0 + pt * 16 + n;
        size_t pix = ((size_t)b * Hn + h) * Wn + w;
        ushort4 ua = *reinterpret_cast<const ushort4*>(A16 + pix * 64 + o0);
        ushort4 uh = *reinterpret_cast<const ushort4*>(Ah16 + pix * 64 + o0);
        float av[4] = { bf2f(ua.x), bf2f(ua.y), bf2f(ua.z), bf2f(ua.w) };
        float hv[4] = { bf2f(uh.x), bf2f(uh.y), bf2f(uh.z), bf2f(uh.w) };
        size_t outb = ((size_t)(b * 64 + o0)) * HWn + (size_t)h * Wn + w;
#pragma unroll
        for (int rg = 0; rg < 4; rg++) {
            float sc = sigm(accC[pt][rg] + bcv[rg]);
            float sr = sigm(accR[pt][rg] + brv[rg]);
            out[outb + (size_t)rg * HWn] = 2.f * av[rg] + (sc + sr) * hv[rg];
        }
    }
}

extern "C" void kernel_launch(void* const* d_in, const int* in_sizes, int n_in,
                              void* d_out, int out_size, void* d_ws, size_t ws_size,
                              hipStream_t stream)
{
    const float* a_low  = (const float*)d_in[0];
    const float* a_high = (const float*)d_in[1];
    const float* pre_w1 = (const float*)d_in[2];
    const float* pre_b1 = (const float*)d_in[3];
    const float* pre_w2 = (const float*)d_in[4];
    const float* pre_b2 = (const float*)d_in[5];
    const float* offc_w = (const float*)d_in[6];
    const float* offc_b = (const float*)d_in[7];
    const float* wc     = (const float*)d_in[8];
    const float* bc     = (const float*)d_in[9];
    const float* offr_w = (const float*)d_in[10];
    const float* offr_b = (const float*)d_in[11];
    const float* wr     = (const float*)d_in[12];
    const float* br     = (const float*)d_in[13];
    float* out = (float*)d_out;
    char* ws8  = (char*)d_ws;

    hipLaunchKernelGGL(k_repack, dim3(96), dim3(256), 0, stream,
                       pre_w1, pre_w2, offc_w, offr_w, wc, wr, ws8);
    // k_pre also writes NCHW bf16 copy of preprocessed a_low into d_out
    // (scratch; fully overwritten by k_dfuse epilogue)
    hipLaunchKernelGGL(k_pre, dim3(2048), dim3(256), 0, stream,
                       a_low, a_high, pre_b1, pre_b2, ws8, (ushort*)d_out);
    hipLaunchKernelGGL(k_om2, dim3(512), dim3(256), 0, stream,
                       (const ushort*)d_out, offc_b, offr_b, ws8);
    hipLaunchKernelGGL(k_dfuse, dim3(4096), dim3(256), 0, stream,
                       bc, br, out, ws8);
}

// Round 4
// 259.838 us; speedup vs baseline: 3.9026x; 1.0661x over previous
//
#include <hip/hip_runtime.h>
#include <hip/hip_fp16.h>
#include <cmath>

// Problem dims: B=4, C=64, H=W=256, k=3
namespace {
constexpr int Bn = 4, Cn = 64, Hn = 256, Wn = 256;
constexpr int HWn = Hn * Wn;              // 65536
// ws layout, BYTE offsets:
constexpr size_t OFF_PRE_LOW  = 0;          // a_low pre, NHWC f16, 33554432 B
constexpr size_t OFF_PRE_HIGH = 33554432;   // a_high pre, NHWC f16
constexpr size_t OFF_OM_COL   = 67108864;   // om col (B,9,H,W) f32, 9437184 B
constexpr size_t OFF_OM_ROW   = 76546048;   // om row f32
constexpr size_t OFF_W1       = 85983232;   // [c][j] 64*32 f32
constexpr size_t OFF_W2       = 85991424;   // [j][o] 32*64 f32
constexpr size_t OFF_WOF16    = 85999616;   // offset-conv weights, half2-dup u32, [c][k][18]
constexpr size_t OFF_WPACK    = 86013440;   // MFMA A-frag packed f16, 2 modes * 12288 halves
// total ~86 MB
}

typedef _Float16 f16x8 __attribute__((ext_vector_type(8)));
typedef float f32x4 __attribute__((ext_vector_type(4)));

__device__ __forceinline__ float sigm(float x) { return 1.f / (1.f + __expf(-x)); }
__device__ __forceinline__ __half2 bc2(unsigned u) { return __builtin_bit_cast(__half2, u); }
__device__ __forceinline__ unsigned u32of(__half2 h) { return __builtin_bit_cast(unsigned, h); }

// ---------------- weight repack (tiny) ----------------
__global__ void k_repack(const float* __restrict__ pw1, const float* __restrict__ pw2,
                         const float* __restrict__ owc, const float* __restrict__ owr,
                         const float* __restrict__ wc,  const float* __restrict__ wr,
                         char* __restrict__ ws8)
{
    float*    W1  = (float*)(ws8 + OFF_W1);
    float*    W2  = (float*)(ws8 + OFF_W2);
    unsigned* Wo2 = (unsigned*)(ws8 + OFF_WOF16);
    __half*   Wp  = (__half*)(ws8 + OFF_WPACK);
    int t = blockIdx.x * 256 + threadIdx.x;
    int stride = gridDim.x * 256;
    for (int i = t; i < 2048; i += stride) { int c = i >> 5, j = i & 31; W1[i] = pw1[j * 64 + c]; }
    for (int i = t; i < 2048; i += stride) { int j = i >> 6, o = i & 63; W2[i] = pw2[o * 32 + j]; }
    // offset-conv weights as duplicated half2: layout [c][k][18]
    for (int i = t; i < 3456; i += stride) {
        int ck = i / 18, d = i - ck * 18;
        float v = (d < 9) ? owc[d * 192 + ck] : owr[(d - 9) * 192 + ck];
        Wo2[i] = u32of(__float2half2_rn(v));
    }
    // MFMA A-fragment pack (f16): k' = tap*64 + c; per mode:
    // Wp[((s*4+wv)*64 + lane)*8 + e] = w[o=wv*16+(lane&15)][k'=32s+(lane>>4)*8+e]
    for (int i = t; i < 24576; i += stride) {
        int m = i >= 12288;
        int rem = i - m * 12288;
        int e = rem & 7, l = (rem >> 3) & 63, wv = (rem >> 9) & 3, s = rem >> 11;
        int kk = 32 * s + (l >> 4) * 8 + e;
        int o = wv * 16 + (l & 15);
        int c = kk & 63, tap = kk >> 6;
        const float* src = m ? wr : wc;
        Wp[i] = __float2half(src[o * 192 + c * 3 + tap]);
    }
}

// ---------------- preprocess: 1x1 conv 64->32->64 ----------------
// NCHW f32 in -> NHWC f16 (ws) + NCHW f16 copy of a_low (d_out scratch)
__global__ __launch_bounds__(256) void k_pre(const float* __restrict__ alow,
                                             const float* __restrict__ ahigh,
                                             const float* __restrict__ b1,
                                             const float* __restrict__ b2,
                                             char* __restrict__ ws8,
                                             __half* __restrict__ anchw)
{
    const float* __restrict__ W1 = (const float*)(ws8 + OFF_W1);
    const float* __restrict__ W2 = (const float*)(ws8 + OFF_W2);
    int t = blockIdx.x * 256 + threadIdx.x;      // [0, 2*B*H*W)
    int tensor = t >> 18;
    int pix = t & 262143;
    int b = pix >> 16;
    int hw = pix & 65535;
    const float* __restrict__ x = (tensor ? ahigh : alow) + (long)b * Cn * HWn + hw;
    __half* __restrict__ outp = (__half*)(ws8 + (tensor ? OFF_PRE_HIGH : OFF_PRE_LOW)) + (long)pix * 64;

    float hreg[32];
#pragma unroll
    for (int j = 0; j < 32; j++) hreg[j] = b1[j];
#pragma unroll 4
    for (int c = 0; c < 64; c++) {
        float xv = x[c * HWn];
        const float* wrow = W1 + c * 32;
#pragma unroll
        for (int j = 0; j < 32; j++) hreg[j] = fmaf(wrow[j], xv, hreg[j]);
    }
    float acc[64];
#pragma unroll
    for (int o = 0; o < 64; o++) acc[o] = b2[o];
#pragma unroll
    for (int j = 0; j < 32; j++) {
        float hv = hreg[j];
        const float* wrow = W2 + j * 64;
#pragma unroll
        for (int o = 0; o < 64; o++) acc[o] = fmaf(wrow[o], hv, acc[o]);
    }
#pragma unroll
    for (int o = 0; o < 64; o += 8) {
        uint4 u;
        u.x = u32of(__float22half2_rn({acc[o + 0], acc[o + 1]}));
        u.y = u32of(__float22half2_rn({acc[o + 2], acc[o + 3]}));
        u.z = u32of(__float22half2_rn({acc[o + 4], acc[o + 5]}));
        u.w = u32of(__float22half2_rn({acc[o + 6], acc[o + 7]}));
        *reinterpret_cast<uint4*>(outp + o) = u;
    }
    if (tensor == 0) {
        __half* __restrict__ np = anchw + (long)b * Cn * HWn + hw;
#pragma unroll
        for (int o = 0; o < 64; o++) np[(long)o * HWn] = __float2half(acc[o]);
    }
}

// ---------------- offset convs: packed-f16, vectorized loads ----------------
// thread = 4 consecutive w of one row. b64 row loads, __hfma2 math.
__global__ __launch_bounds__(256) void k_om2(const __half* __restrict__ Anc,
                                             const float* __restrict__ ocb,
                                             const float* __restrict__ orb,
                                             char* __restrict__ ws8)
{
    const unsigned* __restrict__ Wo2 = (const unsigned*)(ws8 + OFF_WOF16);
    float* __restrict__ omc = (float*)(ws8 + OFF_OM_COL);
    float* __restrict__ omr = (float*)(ws8 + OFF_OM_ROW);
    int t = blockIdx.x * 256 + threadIdx.x;     // [0, B*H*W/4)
    int q = t & 63;
    int h = (t >> 6) & 255;
    int b = t >> 14;
    int w0 = q * 4;
    const __half* __restrict__ base = Anc + ((size_t)b * Cn) * HWn + (size_t)h * Wn + w0;

    const bool topOK = (h > 0), botOK = (h < Hn - 1);
    const bool lOK = (w0 > 0), rOK = (w0 + 4 < Wn);
    const int offT = topOK ? -Wn : 0;
    const int offB = botOK ? Wn : 0;
    const int offL = lOK ? -1 : 0;
    const int offR = rOK ? 4 : 3;

    const __half2 z = __float2half2_rn(0.f);
    const __half hz = __float2half(0.f);
    __half2 aC[9][2], aR[9][2];
#pragma unroll
    for (int d = 0; d < 9; d++) { aC[d][0] = z; aC[d][1] = z; aR[d][0] = z; aR[d][1] = z; }

    for (int c = 0; c < 64; c++) {
        const __half* pc = base + (size_t)c * HWn;
        uint2 qm = *reinterpret_cast<const uint2*>(pc + offT);
        uint2 q0 = *reinterpret_cast<const uint2*>(pc);
        uint2 qp = *reinterpret_cast<const uint2*>(pc + offB);
        __half L = lOK ? pc[offL] : hz;
        __half R = rOK ? pc[offR] : hz;
        __half2 m0 = topOK ? bc2(qm.x) : z, m1 = topOK ? bc2(qm.y) : z;
        __half2 c0 = bc2(q0.x), c1 = bc2(q0.y);
        __half2 p0 = botOK ? bc2(qp.x) : z, p1 = botOK ? bc2(qp.y) : z;
        __half2 X = __halves2half2(L, __low2half(c0));
        __half2 Y = __halves2half2(__high2half(c0), __low2half(c1));
        __half2 Z = __halves2half2(__high2half(c1), R);
        const unsigned* wb = Wo2 + c * 54;     // [k][18]
#pragma unroll
        for (int d = 0; d < 9; d++) {
            __half2 u0 = bc2(wb[d]), u1 = bc2(wb[18 + d]), u2 = bc2(wb[36 + d]);
            aC[d][0] = __hfma2(u0, m0, __hfma2(u1, c0, __hfma2(u2, p0, aC[d][0])));
            aC[d][1] = __hfma2(u0, m1, __hfma2(u1, c1, __hfma2(u2, p1, aC[d][1])));
            __half2 v0 = bc2(wb[9 + d]), v1 = bc2(wb[27 + d]), v2 = bc2(wb[45 + d]);
            aR[d][0] = __hfma2(v0, X, __hfma2(v1, c0, __hfma2(v2, Y, aR[d][0])));
            aR[d][1] = __hfma2(v0, Y, __hfma2(v1, c1, __hfma2(v2, Z, aR[d][1])));
        }
    }

    size_t ob = ((size_t)b * 9) * HWn + (size_t)h * Wn + w0;
#pragma unroll
    for (int d = 0; d < 9; d++) {
        float bcd = ocb[d], brd = orb[d];
        float4 vc = { __low2float(aC[d][0]) + bcd, __high2float(aC[d][0]) + bcd,
                      __low2float(aC[d][1]) + bcd, __high2float(aC[d][1]) + bcd };
        float4 vr = { __low2float(aR[d][0]) + brd, __high2float(aR[d][0]) + brd,
                      __low2float(aR[d][1]) + brd, __high2float(aR[d][1]) + brd };
        *reinterpret_cast<float4*>(omc + ob + (size_t)d * HWn) = vc;
        *reinterpret_cast<float4*>(omr + ob + (size_t)d * HWn) = vr;
    }
}

// ---------------- fused deformable conv (both dirs) + MFMA + epilogue ----------------
// 512 threads, 64 pixels/block. Threads 0..383 each own (mode, tap, pixel):
// decode in regs -> pk_fma gather-blend -> VB (both modes). One barrier.
// Then 8 waves: waves 0-3 mode0 GEMM, waves 4-7 mode1 GEMM. sigma via LDS overlay.
__global__ __launch_bounds__(512, 4) void k_dfuse(const float* __restrict__ bc,
                                                  const float* __restrict__ br,
                                                  float* __restrict__ out,
                                                  char* __restrict__ ws8)
{
    __shared__ __align__(16) unsigned smem[12288];   // 48 KB: VB u32[2][6144]; EX f32[2][4096] overlay

    const __half* __restrict__ A16  = (const __half*)(ws8 + OFF_PRE_LOW);
    const __half* __restrict__ Ah16 = (const __half*)(ws8 + OFF_PRE_HIGH);

    int blk = blockIdx.x;                 // ((b*H + h)*4 + wt)
    int wt = blk & 3, bh = blk >> 2, h = bh & 255, b = bh >> 8;
    int w0 = wt * 64;
    int tid = threadIdx.x;

    // ---- decode + gather (threads 0..383; waves 0-2 mode0, 3-5 mode1) ----
    if (tid < 384) {
        int m = tid >= 192 ? 1 : 0;
        int r = tid - m * 192;
        int tap = r >> 6, p = r & 63;
        int w = w0 + p;
        const float* __restrict__ om = (const float*)(ws8 + (m ? OFF_OM_ROW : OFF_OM_COL));
        size_t ob = ((size_t)b * 9 * Hn + h) * Wn + w;
        float dy = om[ob + (size_t)tap * HWn];
        float dx = om[ob + (size_t)(3 + tap) * HWn];
        float mm = om[ob + (size_t)(6 + tap) * HWn];
        float mask = sigm(mm);
        float py = dy + (float)h + (m ? 0.f : (float)(tap - 1));
        float px = dx + (float)w + (m ? (float)(tap - 1) : 0.f);
        float fy = floorf(py), fx = floorf(px);
        float ty = py - fy, tx = px - fx;
        int y0 = (int)fy, x0 = (int)fx;
        int y1 = y0 + 1, x1 = x0 + 1;
        float vy0 = ((unsigned)y0 < (unsigned)Hn) ? 1.f : 0.f;
        float vy1 = ((unsigned)y1 < (unsigned)Hn) ? 1.f : 0.f;
        float vx0 = ((unsigned)x0 < (unsigned)Wn) ? 1.f : 0.f;
        float vx1 = ((unsigned)x1 < (unsigned)Wn) ? 1.f : 0.f;
        int y0c = min(max(y0, 0), Hn - 1), y1c = min(max(y1, 0), Hn - 1);
        int x0c = min(max(x0, 0), Wn - 1), x1c = min(max(x1, 0), Wn - 1);
        float ry = 1.f - ty, rx = 1.f - tx;
        int pbase = b * HWn;
        __half2 wh[4];
        wh[0] = __float2half2_rn(ry * rx * mask * vy0 * vx0);
        wh[1] = __float2half2_rn(ry * tx * mask * vy0 * vx1);
        wh[2] = __float2half2_rn(ty * rx * mask * vy1 * vx0);
        wh[3] = __float2half2_rn(ty * tx * mask * vy1 * vx1);
        int cb[4];
        cb[0] = (pbase + y0c * Wn + x0c) * 8;     // uint4-index: pix*128B/16
        cb[1] = (pbase + y0c * Wn + x1c) * 8;
        cb[2] = (pbase + y1c * Wn + x0c) * 8;
        cb[3] = (pbase + y1c * Wn + x1c) * 8;
        const uint4* __restrict__ Au = (const uint4*)A16;
        const __half2 z = __float2half2_rn(0.f);
#pragma unroll
        for (int c4 = 0; c4 < 4; c4++) {
            __half2 hs[8];
#pragma unroll
            for (int j = 0; j < 8; j++) hs[j] = z;
#pragma unroll
            for (int i = 0; i < 4; i++) {
                uint4 ua = Au[cb[i] + c4 * 2];
                uint4 ub = Au[cb[i] + c4 * 2 + 1];
                hs[0] = __hfma2(bc2(ua.x), wh[i], hs[0]);
                hs[1] = __hfma2(bc2(ua.y), wh[i], hs[1]);
                hs[2] = __hfma2(bc2(ua.z), wh[i], hs[2]);
                hs[3] = __hfma2(bc2(ua.w), wh[i], hs[3]);
                hs[4] = __hfma2(bc2(ub.x), wh[i], hs[4]);
                hs[5] = __hfma2(bc2(ub.y), wh[i], hs[5]);
                hs[6] = __hfma2(bc2(ub.z), wh[i], hs[6]);
                hs[7] = __hfma2(bc2(ub.w), wh[i], hs[7]);
            }
            int g0 = tap * 8 + c4 * 2;
            uint4 lo = { u32of(hs[0]), u32of(hs[1]), u32of(hs[2]), u32of(hs[3]) };
            uint4 hi = { u32of(hs[4]), u32of(hs[5]), u32of(hs[6]), u32of(hs[7]) };
            *reinterpret_cast<uint4*>(&smem[m * 6144 + (g0 + 0) * 256 + p * 4]) = lo;
            *reinterpret_cast<uint4*>(&smem[m * 6144 + (g0 + 1) * 256 + p * 4]) = hi;
        }
    }
    __syncthreads();

    // ---- GEMM: wave wv: mode = wv>>2, o-slice = (wv&3)*16 ----
    int wv = tid >> 6;
    int lane = tid & 63;
    int m = wv >> 2;
    int wq = wv & 3;
    int kb = lane >> 4, n = lane & 15;
    const f16x8* __restrict__ Wp = reinterpret_cast<const f16x8*>(ws8 + OFF_WPACK + (size_t)m * 24576);
    f32x4 zero = {0.f, 0.f, 0.f, 0.f};
    f32x4 acc[4] = {zero, zero, zero, zero};
#pragma unroll
    for (int s = 0; s < 6; s++) {
        f16x8 af = Wp[(s * 4 + wq) * 64 + lane];
#pragma unroll
        for (int pt = 0; pt < 4; pt++) {
            f16x8 bf = *reinterpret_cast<const f16x8*>(&smem[m * 6144 + (s * 4 + kb) * 256 + (pt * 16 + n) * 4]);
            acc[pt] = __builtin_amdgcn_mfma_f32_16x16x32_f16(af, bf, acc[pt], 0, 0, 0);
        }
    }
    // sigma in regs
    const float* __restrict__ bias = m ? br : bc;
    float bv[4];
#pragma unroll
    for (int rg = 0; rg < 4; rg++) bv[rg] = bias[wq * 16 + kb * 4 + rg];
    float sg[4][4];
#pragma unroll
    for (int pt = 0; pt < 4; pt++)
#pragma unroll
        for (int rg = 0; rg < 4; rg++) sg[pt][rg] = sigm(acc[pt][rg] + bv[rg]);
    __syncthreads();
    // EX overlay: [m][o][p] f32
    float* EX = reinterpret_cast<float*>(smem);
#pragma unroll
    for (int pt = 0; pt < 4; pt++)
#pragma unroll
        for (int rg = 0; rg < 4; rg++)
            EX[m * 4096 + (wq * 16 + kb * 4 + rg) * 64 + (pt * 16 + n)] = sg[pt][rg];
    __syncthreads();

    // ---- epilogue: thread t: pixel p = t&63, o-group = t>>6 (8 o's) ----
    int p = tid & 63, og = tid >> 6;
    int o0 = og * 8;
    size_t pix = ((size_t)b * Hn + h) * Wn + (w0 + p);
    uint4 ua = *reinterpret_cast<const uint4*>(A16 + pix * 64 + o0);
    uint4 uh = *reinterpret_cast<const uint4*>(Ah16 + pix * 64 + o0);
    const __half* ap = reinterpret_cast<const __half*>(&ua);
    const __half* hp = reinterpret_cast<const __half*>(&uh);
    size_t outb = ((size_t)b * 64 + o0) * HWn + (size_t)h * Wn + w0 + p;
#pragma unroll
    for (int j = 0; j < 8; j++) {
        float sc = EX[(o0 + j) * 64 + p];
        float sr = EX[4096 + (o0 + j) * 64 + p];
        float av = __half2float(ap[j]);
        float hv = __half2float(hp[j]);
        out[outb + (size_t)j * HWn] = 2.f * av + (sc + sr) * hv;
    }
}

extern "C" void kernel_launch(void* const* d_in, const int* in_sizes, int n_in,
                              void* d_out, int out_size, void* d_ws, size_t ws_size,
                              hipStream_t stream)
{
    const float* a_low  = (const float*)d_in[0];
    const float* a_high = (const float*)d_in[1];
    const float* pre_w1 = (const float*)d_in[2];
    const float* pre_b1 = (const float*)d_in[3];
    const float* pre_w2 = (const float*)d_in[4];
    const float* pre_b2 = (const float*)d_in[5];
    const float* offc_w = (const float*)d_in[6];
    const float* offc_b = (const float*)d_in[7];
    const float* wc     = (const float*)d_in[8];
    const float* bc     = (const float*)d_in[9];
    const float* offr_w = (const float*)d_in[10];
    const float* offr_b = (const float*)d_in[11];
    const float* wr     = (const float*)d_in[12];
    const float* br     = (const float*)d_in[13];
    float* out = (float*)d_out;
    char* ws8  = (char*)d_ws;

    hipLaunchKernelGGL(k_repack, dim3(128), dim3(256), 0, stream,
                       pre_w1, pre_w2, offc_w, offr_w, wc, wr, ws8);
    // k_pre also writes NCHW f16 copy of preprocessed a_low into d_out
    // (scratch; fully overwritten by k_dfuse epilogue)
    hipLaunchKernelGGL(k_pre, dim3(2048), dim3(256), 0, stream,
                       a_low, a_high, pre_b1, pre_b2, ws8, (__half*)d_out);
    hipLaunchKernelGGL(k_om2, dim3(256), dim3(256), 0, stream,
                       (const __half*)d_out, offc_b, offr_b, ws8);
    hipLaunchKernelGGL(k_dfuse, dim3(4096), dim3(512), 0, stream,
                       bc, br, out, ws8);
}